// Round 11
// baseline (786.311 us; speedup 1.0000x reference)
//
#include <hip/hip_runtime.h>
#include <math.h>

#define N_NODES 100000
#define N_EDGES 1600000
#define DIM 32
#define N_GROUPS 64
#define BN_EPS 1e-5f

#define BIN_NODES 128
#define NBINS ((N_NODES + BIN_NODES - 1) / BIN_NODES)   // 782
#define EPB_HIST 8192
#define HIST_BLOCKS ((N_EDGES + EPB_HIST - 1) / EPB_HIST)  // 196

#define ACCS 33   // accf row stride (floats): odd -> ds_add/read banks spread
#define HLS  40   // hl row stride (shorts): 80 B rows, 16B-aligned b128, 2-way max

typedef __attribute__((ext_vector_type(8))) short short8;   // 8 bf16 (4 VGPRs)
typedef __attribute__((ext_vector_type(4))) float f32x4;

// ---- monotone float<->uint encoding for atomic max on floats ----
__device__ __forceinline__ unsigned enc_f32(float f) {
    unsigned u = __float_as_uint(f);
    return (u & 0x80000000u) ? ~u : (u | 0x80000000u);
}
__device__ __forceinline__ float dec_f32(unsigned u) {
    return (u & 0x80000000u) ? __uint_as_float(u & 0x7FFFFFFFu) : __uint_as_float(~u);
}
// fp32 -> bf16 bits (RNE)
__device__ __forceinline__ unsigned short f2bf(float f) {
    unsigned u = __float_as_uint(f);
    u += 0x7FFFu + ((u >> 16) & 1u);
    return (unsigned short)(u >> 16);
}
__device__ __forceinline__ float bf2f(unsigned short s) {
    return __uint_as_float((unsigned)s << 16);
}

// Fold BN into weights (+bf16 copy). Block 5 zeros out/segmx/bincnt (replaces 3 memsets).
__global__ void fold_kernel(const float* __restrict__ lin_W, const float* __restrict__ lin_b,
                            const float* __restrict__ lin_gamma, const float* __restrict__ lin_beta,
                            const float* __restrict__ lin_mean, const float* __restrict__ lin_var,
                            const float* __restrict__ conv_W, const float* __restrict__ conv_b,
                            const float* __restrict__ conv_gamma, const float* __restrict__ conv_beta,
                            const float* __restrict__ conv_mean, const float* __restrict__ conv_var,
                            float* __restrict__ Wf, float* __restrict__ shf,
                            unsigned short* __restrict__ Wfb,
                            float* __restrict__ out, unsigned* __restrict__ segmx,
                            int* __restrict__ bincnt)
{
    int l = blockIdx.x;      // 0..2 = lin, 3..4 = conv, 5 = zero-fill
    int t = threadIdx.x;
    if (l == 5) {
        out[t] = 0.f; out[t + 1024] = 0.f;
        segmx[t] = 0; segmx[t + 1024] = 0;
        if (t < NBINS) bincnt[t] = 0;
        return;
    }
    const float *W, *b, *gm, *bt, *mn, *vr;
    if (l < 3) {
        W = lin_W + l * DIM * DIM; b = lin_b + l * DIM; gm = lin_gamma + l * DIM;
        bt = lin_beta + l * DIM;   mn = lin_mean + l * DIM; vr = lin_var + l * DIM;
    } else {
        int c = l - 3;
        W = conv_W + c * DIM * DIM; b = conv_b + c * DIM; gm = conv_gamma + c * DIM;
        bt = conv_beta + c * DIM;   mn = conv_mean + c * DIM; vr = conv_var + c * DIM;
    }
    int j = t & (DIM - 1);
    float scale = gm[j] / sqrtf(vr[j] + BN_EPS);
    float w = W[t] * scale;
    Wf[l * DIM * DIM + t] = w;
    Wfb[l * DIM * DIM + t] = f2bf(w);
    if (t < DIM) shf[l * DIM + t] = (b[t] - mn[t]) * scale + bt[t];
}

// ================= bin-grouped edge build =================
__global__ __launch_bounds__(256) void binhist_kernel(const int* __restrict__ dst,
                                                      int* __restrict__ bincnt,
                                                      int* __restrict__ blockcnt) {
    __shared__ int cnt[NBINS];
    int t = threadIdx.x;
    for (int b = t; b < NBINS; b += 256) cnt[b] = 0;
    __syncthreads();
    int base = blockIdx.x * EPB_HIST;
    for (int i = 0; i < EPB_HIST / 256; ++i) {
        int e = base + i * 256 + t;
        if (e < N_EDGES) atomicAdd(&cnt[dst[e] >> 7], 1);
    }
    __syncthreads();
    for (int b = t; b < NBINS; b += 256) {
        int c = cnt[b];
        blockcnt[(size_t)blockIdx.x * NBINS + b] = c;
        if (c > 0) atomicAdd(&bincnt[b], c);
    }
}

__global__ __launch_bounds__(1024) void binscan_kernel(const int* __restrict__ bincnt,
                                                       int* __restrict__ binoff,
                                                       int* __restrict__ bincur) {
    __shared__ int s[1024];
    int t = threadIdx.x;
    int c = (t < NBINS) ? bincnt[t] : 0;
    s[t] = c;
    __syncthreads();
    for (int off = 1; off < 1024; off <<= 1) {
        int u = (t >= off) ? s[t - off] : 0;
        __syncthreads();
        s[t] += u;
        __syncthreads();
    }
    if (t < NBINS) { binoff[t] = s[t] - c; bincur[t] = s[t] - c; }
    if (t == 0) binoff[NBINS] = N_EDGES;
}

__global__ __launch_bounds__(256) void binscatter_kernel(const int* __restrict__ src,
                                                         const int* __restrict__ dst,
                                                         int* __restrict__ bincur,
                                                         unsigned* __restrict__ binbuf,
                                                         const int* __restrict__ blockcnt) {
    __shared__ int pos[NBINS];
    int t = threadIdx.x;
    for (int b = t; b < NBINS; b += 256) {
        int c = blockcnt[(size_t)blockIdx.x * NBINS + b];
        pos[b] = (c > 0) ? atomicAdd(&bincur[b], c) : 0;
    }
    __syncthreads();
    int base = blockIdx.x * EPB_HIST;
    for (int i = 0; i < EPB_HIST / 256; ++i) {
        int e = base + i * 256 + t;
        if (e < N_EDGES) {
            int d = dst[e];
            int bin = d >> 7;
            int p = atomicAdd(&pos[bin], 1);
            binbuf[p] = ((unsigned)(d & 127) << 17) | (unsigned)src[e];
        }
    }
}

// counting sort within bin -> node-grouped edges; esrc packs (tile-local dst)<<17 | src
__global__ __launch_bounds__(256) void binsort_kernel(const unsigned* __restrict__ binbuf,
                                                      const int* __restrict__ binoff,
                                                      unsigned* __restrict__ esrc,
                                                      int* __restrict__ nodeptr) {
    __shared__ int cnt[BIN_NODES];
    __shared__ int sc[BIN_NODES];
    int t = threadIdx.x;
    int bin = blockIdx.x;
    int beg = binoff[bin], end = binoff[bin + 1];
    if (t < BIN_NODES) cnt[t] = 0;
    __syncthreads();
    for (int e = beg + t; e < end; e += 256)
        atomicAdd(&cnt[binbuf[e] >> 17], 1);
    __syncthreads();
    int v = (t < BIN_NODES) ? cnt[t] : 0;
    if (t < BIN_NODES) sc[t] = v;
    __syncthreads();
    for (int off = 1; off < BIN_NODES; off <<= 1) {
        int u = (t < BIN_NODES && t >= off) ? sc[t - off] : 0;
        __syncthreads();
        if (t < BIN_NODES) sc[t] += u;
        __syncthreads();
    }
    if (t < BIN_NODES) {
        int excl = sc[t] - v;
        cnt[t] = excl;
        nodeptr[bin * BIN_NODES + t] = beg + excl;
    }
    __syncthreads();
    for (int e = beg + t; e < end; e += 256) {
        unsigned pe = binbuf[e];
        int dl = (int)(pe >> 17);
        int p = atomicAdd(&cnt[dl], 1);
        esrc[beg + p] = ((unsigned)(dl & 15) << 17) | (pe & 0x1FFFFu);
    }
}

// ===== fused GIN layer v2: EDGE-PARALLEL LDS gather + MFMA conv + MFMA lin + epilogue.
// Block = 256 = 4 waves; wave owns one 16-node tile. Gather: lane=(slot0-1,col0-31)
// streams the tile's edge list with ds_add into wave-private fp32 accf — every round
// independent (loads pipeline; no serial acc chain).
__global__ __launch_bounds__(256) void gin_fused_kernel(
        const unsigned short* __restrict__ xb,    // [N,32] bf16 layer input (padded)
        const unsigned* __restrict__ esrc,        // packed (dl&15)<<17 | src
        const int* __restrict__ nodeptr,
        const unsigned short* __restrict__ Wcb, const float* __restrict__ shc,
        const unsigned short* __restrict__ Wlb, const float* __restrict__ shl,
        const int* __restrict__ batch, const float* __restrict__ lw_ptr,
        unsigned short* __restrict__ xnextb,      // bf16 out (padded ws; may be null)
        float* __restrict__ xoutf,                // fp32 conv out (may be null)
        float* __restrict__ Z,                    // [N,32] +=
        unsigned* __restrict__ segmax)            // [G,32] encoded
{
    __shared__ float accf[4][16 * ACCS];                       // 8.4 KB
    __shared__ __align__(16) unsigned short hl[4][16 * HLS];   // 5 KB
    __shared__ unsigned segloc[8 * DIM];                       // 1 KB
    int t = threadIdx.x;
    segloc[t] = 0;

    int wv = t >> 6, lane = t & 63;
    int col = lane & 31, slot = lane >> 5;
    int m = lane & 15, kg = lane >> 4;

    // B fragments: B[k=kg*8+j][n=m]
    short8 bc0, bc1, bl0, bl1;
#pragma unroll
    for (int j = 0; j < 8; ++j) {
        int k = kg * 8 + j;
        bc0[j] = (short)Wcb[k * DIM + m];
        bc1[j] = (short)Wcb[k * DIM + 16 + m];
        bl0[j] = (short)Wlb[k * DIM + m];
        bl1[j] = (short)Wlb[k * DIM + 16 + m];
    }
    float shc0 = shc[m], shc1 = shc[m + 16];
    float shl0 = shl[m], shl1 = shl[m + 16];
    float lw = lw_ptr[0];
    int blk0 = blockIdx.x * 64;
    int gfirst = batch[blk0 < N_NODES ? blk0 : N_NODES - 1];
    int row0 = blk0 + wv * 16;
    __syncthreads();   // segloc init visible block-wide

    // ---- init accf with self rows (wave-private; same-wave LDS is in-order) ----
    for (int i = slot; i < 16; i += 2)
        accf[wv][i * ACCS + col] = bf2f(xb[(size_t)(row0 + i) * DIM + col]);

    // ---- edge-parallel gather: tile edges [nodeptr[row0], nodeptr[row0+16]) ----
    {
        int beg = nodeptr[row0], end = nodeptr[row0 + 16];
        int e = beg + slot;
        for (; e + 2 < end; e += 4) {              // 2 independent rounds in flight
            unsigned p0 = esrc[e], p1 = esrc[e + 2];
            float v0 = bf2f(xb[(size_t)(p0 & 0x1FFFFu) * DIM + col]);
            float v1 = bf2f(xb[(size_t)(p1 & 0x1FFFFu) * DIM + col]);
            atomicAdd(&accf[wv][(p0 >> 17) * ACCS + col], v0);
            atomicAdd(&accf[wv][(p1 >> 17) * ACCS + col], v1);
        }
        for (; e < end; e += 2) {
            unsigned pe = esrc[e];
            atomicAdd(&accf[wv][(pe >> 17) * ACCS + col],
                      bf2f(xb[(size_t)(pe & 0x1FFFFu) * DIM + col]));
        }
    }

    // ---- conv MLP via MFMA: A-frag straight from accf ----
    short8 a;
#pragma unroll
    for (int j = 0; j < 8; ++j)
        a[j] = (short)f2bf(accf[wv][m * ACCS + kg * 8 + j]);
    f32x4 d0 = {0.f, 0.f, 0.f, 0.f}, d1 = {0.f, 0.f, 0.f, 0.f};
    d0 = __builtin_amdgcn_mfma_f32_16x16x32_bf16(a, bc0, d0, 0, 0, 0);
    d1 = __builtin_amdgcn_mfma_f32_16x16x32_bf16(a, bc1, d1, 0, 0, 0);
    float hp0[4], hp1[4];
#pragma unroll
    for (int r = 0; r < 4; ++r) {
        float a0 = d0[r] + shc0, a1 = d1[r] + shc1;
        hp0[r] = a0 > 0.f ? a0 : expm1f(a0);
        hp1[r] = a1 > 0.f ? a1 : expm1f(a1);
    }
    // hp (D-layout) -> hl bf16 (row-major) for lin A-frag / xnextb staging
#pragma unroll
    for (int r = 0; r < 4; ++r) {
        hl[wv][(kg * 4 + r) * HLS + m] = f2bf(hp0[r]);
        hl[wv][(kg * 4 + r) * HLS + 16 + m] = f2bf(hp1[r]);
    }
    if (xoutf) {
#pragma unroll
        for (int r = 0; r < 4; ++r) {
            int row = row0 + kg * 4 + r;
            if (row < N_NODES) {
                xoutf[(size_t)row * DIM + m] = hp0[r];
                xoutf[(size_t)row * DIM + 16 + m] = hp1[r];
            }
        }
    }
    if (xnextb) {          // coalesced bf16 out from LDS: lane -> (row i, quarter q)
        int i = lane >> 2, q = lane & 3;
        uint4 pk = *(const uint4*)&hl[wv][i * HLS + q * 8];
        *(uint4*)(xnextb + (size_t)(row0 + i) * DIM + q * 8) = pk;
    }

    // ---- lin MLP via MFMA ----
    short8 a2 = *(const short8*)&hl[wv][m * HLS + kg * 8];
    f32x4 e0 = {0.f, 0.f, 0.f, 0.f}, e1 = {0.f, 0.f, 0.f, 0.f};
    e0 = __builtin_amdgcn_mfma_f32_16x16x32_bf16(a2, bl0, e0, 0, 0, 0);
    e1 = __builtin_amdgcn_mfma_f32_16x16x32_bf16(a2, bl1, e1, 0, 0, 0);
#pragma unroll
    for (int r = 0; r < 4; ++r) {
        int row = row0 + kg * 4 + r;
        if (row < N_NODES) {
            float a0 = e0[r] + shl0, a1 = e1[r] + shl1;
            float z0 = a0 > 0.f ? a0 : expm1f(a0);
            float z1 = a1 > 0.f ? a1 : expm1f(a1);
            float zw0 = lw * z0, zw1 = lw * z1;
            size_t zi = (size_t)row * DIM;
            Z[zi + m] += zw0;
            Z[zi + 16 + m] += zw1;
            int g = batch[row];
            int go = g - gfirst;
            if (go < 8) {
                atomicMax(&segloc[go * DIM + m], enc_f32(zw0));
                atomicMax(&segloc[go * DIM + 16 + m], enc_f32(zw1));
            } else {
                atomicMax(&segmax[g * DIM + m], enc_f32(zw0));
                atomicMax(&segmax[g * DIM + 16 + m], enc_f32(zw1));
            }
        }
    }
    __syncthreads();
    unsigned v = segloc[t];
    if (v) atomicMax(&segmax[(gfirst + (t >> 5)) * DIM + (t & 31)], v);
}

// ===== layer-0 lin MLP via MFMA; reads fp32 x0, emits bf16 mirror (kills convert) =====
__global__ __launch_bounds__(256) void linZ_first_kernel(
        const float* __restrict__ x0,            // [N,32] fp32
        unsigned short* __restrict__ x0b,        // [N,32] bf16 out (padded)
        const unsigned short* __restrict__ Wb,   // [32,32] bf16 folded lin W
        const float* __restrict__ shf,
        const int* __restrict__ batch,           // [N] sorted
        const float* __restrict__ lw_ptr,
        float* __restrict__ Z,                   // [N,32] write
        unsigned* __restrict__ segmax)
{
    __shared__ unsigned segloc[8 * DIM];
    int t = threadIdx.x;
    segloc[t] = 0;

    int wv = t >> 6, lane = t & 63;
    int m = lane & 15, kg = lane >> 4;

    short8 b0, b1;
#pragma unroll
    for (int j = 0; j < 8; ++j) {
        int k = kg * 8 + j;
        b0[j] = (short)Wb[k * DIM + m];
        b1[j] = (short)Wb[k * DIM + 16 + m];
    }
    float sh0 = shf[m], sh1 = shf[m + 16];
    float lw = lw_ptr[0];
    int blk0 = blockIdx.x * 64;
    int gfirst = batch[blk0 < N_NODES ? blk0 : N_NODES - 1];
    int row0 = blk0 + wv * 16;
    __syncthreads();

    if (row0 < N_NODES) {                        // N%16==0: whole tile valid or not
        const float* rp = x0 + (size_t)(row0 + m) * DIM + kg * 8;
        float4 v0 = *(const float4*)rp;
        float4 v1 = *(const float4*)(rp + 4);
        short8 a;
        a[0] = (short)f2bf(v0.x); a[1] = (short)f2bf(v0.y);
        a[2] = (short)f2bf(v0.z); a[3] = (short)f2bf(v0.w);
        a[4] = (short)f2bf(v1.x); a[5] = (short)f2bf(v1.y);
        a[6] = (short)f2bf(v1.z); a[7] = (short)f2bf(v1.w);
        *(short8*)(x0b + (size_t)(row0 + m) * DIM + kg * 8) = a;   // bf16 mirror

        f32x4 d0 = {0.f, 0.f, 0.f, 0.f}, d1 = {0.f, 0.f, 0.f, 0.f};
        d0 = __builtin_amdgcn_mfma_f32_16x16x32_bf16(a, b0, d0, 0, 0, 0);
        d1 = __builtin_amdgcn_mfma_f32_16x16x32_bf16(a, b1, d1, 0, 0, 0);
#pragma unroll
        for (int r = 0; r < 4; ++r) {
            int row = row0 + kg * 4 + r;
            float a0 = d0[r] + sh0;
            float a1 = d1[r] + sh1;
            float z0 = a0 > 0.f ? a0 : expm1f(a0);
            float z1 = a1 > 0.f ? a1 : expm1f(a1);
            size_t zi = (size_t)row * DIM;
            Z[zi + m] = lw * z0;
            Z[zi + 16 + m] = lw * z1;
            int g = batch[row];
            int go = g - gfirst;
            if (go < 8) {
                atomicMax(&segloc[go * DIM + m], enc_f32(z0));
                atomicMax(&segloc[go * DIM + 16 + m], enc_f32(z1));
            } else {
                atomicMax(&segmax[g * DIM + m], enc_f32(z0));
                atomicMax(&segmax[g * DIM + 16 + m], enc_f32(z1));
            }
        }
    }
    __syncthreads();
    unsigned v = segloc[t];
    if (v) atomicMax(&segmax[(gfirst + (t >> 5)) * DIM + (t & 31)], v);
}

// out[g][j] += decode(segmax[g][j]); reset segmax for the next layer's atomics.
__global__ void add_out_kernel(unsigned* __restrict__ segmax, float* __restrict__ out) {
    int t = blockIdx.x * blockDim.x + threadIdx.x;  // 2048
    out[t] += dec_f32(segmax[t]);
    segmax[t] = 0;
}

extern "C" void kernel_launch(void* const* d_in, const int* in_sizes, int n_in,
                              void* d_out, int out_size, void* d_ws, size_t ws_size,
                              hipStream_t stream) {
    const float* x0        = (const float*)d_in[0];
    const int*   ei        = (const int*)d_in[1];     // (2,E): row0=src, row1=dst
    const int*   batch     = (const int*)d_in[2];
    const float* lw        = (const float*)d_in[3];
    const float* lin_W     = (const float*)d_in[4];
    const float* lin_b     = (const float*)d_in[5];
    const float* lin_gamma = (const float*)d_in[6];
    const float* lin_beta  = (const float*)d_in[7];
    const float* lin_mean  = (const float*)d_in[8];
    const float* lin_var   = (const float*)d_in[9];
    const float* conv_W    = (const float*)d_in[10];
    const float* conv_b    = (const float*)d_in[11];
    const float* conv_gamma= (const float*)d_in[12];
    const float* conv_beta = (const float*)d_in[13];
    const float* conv_mean = (const float*)d_in[14];
    const float* conv_var  = (const float*)d_in[15];

    float* out  = (float*)d_out;                 // [G*32]
    float* Z    = out + N_GROUPS * DIM;          // [N*32]
    float* xout = Z + (size_t)N_NODES * DIM;     // [N*32] final x (fp32 conv out, layer 2)

    char* p = (char*)d_ws;
    unsigned short* x0b     = (unsigned short*)p; p += ((size_t)N_NODES * DIM + 8192) * sizeof(unsigned short);
    unsigned short* xbufb   = (unsigned short*)p; p += ((size_t)N_NODES * DIM + 8192) * sizeof(unsigned short);
    unsigned*       binbuf  = (unsigned*)p;       p += (size_t)N_EDGES * sizeof(unsigned);
    unsigned*       esrc    = (unsigned*)p;       p += (size_t)N_EDGES * sizeof(unsigned);
    int*            nodeptr = (int*)p;            p += (NBINS * BIN_NODES + 1) * sizeof(int);
    int*            blockcnt= (int*)p;            p += (size_t)HIST_BLOCKS * NBINS * sizeof(int);
    int*            bincnt  = (int*)p;            p += NBINS * sizeof(int);
    int*            binoff  = (int*)p;            p += (NBINS + 1) * sizeof(int);
    int*            bincur  = (int*)p;            p += NBINS * sizeof(int);
    unsigned*       segmx   = (unsigned*)p;       p += N_GROUPS * DIM * sizeof(unsigned);
    float*          Wf      = (float*)p;          p += 5 * DIM * DIM * sizeof(float);
    float*          shf     = (float*)p;          p += 5 * DIM * sizeof(float);
    unsigned short* Wfb     = (unsigned short*)p; p += 5 * DIM * DIM * sizeof(unsigned short);

    const int* src = ei;
    const int* dst = ei + N_EDGES;

    const int gf_blocks = (N_NODES + 63) / 64;   // 1563 (covers linZ_first + gin_fused)

    fold_kernel<<<6, 1024, 0, stream>>>(lin_W, lin_b, lin_gamma, lin_beta, lin_mean, lin_var,
                                        conv_W, conv_b, conv_gamma, conv_beta, conv_mean, conv_var,
                                        Wf, shf, Wfb, out, segmx, bincnt);

    // ---- CSR build (tile-local packed esrc) ----
    binhist_kernel<<<HIST_BLOCKS, 256, 0, stream>>>(dst, bincnt, blockcnt);
    binscan_kernel<<<1, 1024, 0, stream>>>(bincnt, binoff, bincur);
    binscatter_kernel<<<HIST_BLOCKS, 256, 0, stream>>>(src, dst, bincur, binbuf, blockcnt);
    binsort_kernel<<<NBINS, 256, 0, stream>>>(binbuf, binoff, esrc, nodeptr);

    // ---- layer 0 (also emits x0b bf16 mirror) ----
    linZ_first_kernel<<<gf_blocks, 256, 0, stream>>>(x0, x0b, Wfb, shf, batch, lw, Z, segmx);
    add_out_kernel<<<8, 256, 0, stream>>>(segmx, out);

    // ---- layer 1 ----
    gin_fused_kernel<<<gf_blocks, 256, 0, stream>>>(x0b, esrc, nodeptr,
                                                    Wfb + 3 * DIM * DIM, shf + 3 * DIM,
                                                    Wfb + 1 * DIM * DIM, shf + 1 * DIM,
                                                    batch, lw + 1,
                                                    xbufb, (float*)nullptr, Z, segmx);
    add_out_kernel<<<8, 256, 0, stream>>>(segmx, out);

    // ---- layer 2 ----
    gin_fused_kernel<<<gf_blocks, 256, 0, stream>>>(xbufb, esrc, nodeptr,
                                                    Wfb + 4 * DIM * DIM, shf + 4 * DIM,
                                                    Wfb + 2 * DIM * DIM, shf + 2 * DIM,
                                                    batch, lw + 2,
                                                    (unsigned short*)nullptr, xout, Z, segmx);
    add_out_kernel<<<8, 256, 0, stream>>>(segmx, out);
}

// Round 12
// 266.791 us; speedup vs baseline: 2.9473x; 2.9473x over previous
//
#include <hip/hip_runtime.h>
#include <math.h>

#define N_NODES 100000
#define N_EDGES 1600000
#define DIM 32
#define N_GROUPS 64
#define BN_EPS 1e-5f

#define BIN_NODES 128
#define NBINS ((N_NODES + BIN_NODES - 1) / BIN_NODES)   // 782
#define EPB_HIST 8192
#define HIST_BLOCKS ((N_EDGES + EPB_HIST - 1) / EPB_HIST)  // 196

#define HLS 40    // hl row stride in shorts (80 B): 16B-aligned b128, worst 2-way banks

typedef __attribute__((ext_vector_type(8))) short short8;   // 8 bf16 (4 VGPRs)
typedef __attribute__((ext_vector_type(4))) float f32x4;

// ---- monotone float<->uint encoding for atomic max on floats ----
__device__ __forceinline__ unsigned enc_f32(float f) {
    unsigned u = __float_as_uint(f);
    return (u & 0x80000000u) ? ~u : (u | 0x80000000u);
}
__device__ __forceinline__ float dec_f32(unsigned u) {
    return (u & 0x80000000u) ? __uint_as_float(u & 0x7FFFFFFFu) : __uint_as_float(~u);
}
// fp32 -> bf16 bits (RNE)
__device__ __forceinline__ unsigned short f2bf(float f) {
    unsigned u = __float_as_uint(f);
    u += 0x7FFFu + ((u >> 16) & 1u);
    return (unsigned short)(u >> 16);
}

// Fold BN into weights (+bf16 copy). Block 5 zeros out/segmx/bincnt.
__global__ void fold_kernel(const float* __restrict__ lin_W, const float* __restrict__ lin_b,
                            const float* __restrict__ lin_gamma, const float* __restrict__ lin_beta,
                            const float* __restrict__ lin_mean, const float* __restrict__ lin_var,
                            const float* __restrict__ conv_W, const float* __restrict__ conv_b,
                            const float* __restrict__ conv_gamma, const float* __restrict__ conv_beta,
                            const float* __restrict__ conv_mean, const float* __restrict__ conv_var,
                            float* __restrict__ Wf, float* __restrict__ shf,
                            unsigned short* __restrict__ Wfb,
                            float* __restrict__ out, unsigned* __restrict__ segmx,
                            int* __restrict__ bincnt)
{
    int l = blockIdx.x;      // 0..2 = lin, 3..4 = conv, 5 = zero-fill
    int t = threadIdx.x;
    if (l == 5) {
        out[t] = 0.f; out[t + 1024] = 0.f;
        segmx[t] = 0; segmx[t + 1024] = 0;
        if (t < NBINS) bincnt[t] = 0;
        return;
    }
    const float *W, *b, *gm, *bt, *mn, *vr;
    if (l < 3) {
        W = lin_W + l * DIM * DIM; b = lin_b + l * DIM; gm = lin_gamma + l * DIM;
        bt = lin_beta + l * DIM;   mn = lin_mean + l * DIM; vr = lin_var + l * DIM;
    } else {
        int c = l - 3;
        W = conv_W + c * DIM * DIM; b = conv_b + c * DIM; gm = conv_gamma + c * DIM;
        bt = conv_beta + c * DIM;   mn = conv_mean + c * DIM; vr = conv_var + c * DIM;
    }
    int j = t & (DIM - 1);
    float scale = gm[j] / sqrtf(vr[j] + BN_EPS);
    float w = W[t] * scale;
    Wf[l * DIM * DIM + t] = w;
    Wfb[l * DIM * DIM + t] = f2bf(w);
    if (t < DIM) shf[l * DIM + t] = (b[t] - mn[t]) * scale + bt[t];
}

// ================= bin-grouped edge build (proven) =================
__global__ __launch_bounds__(256) void binhist_kernel(const int* __restrict__ dst,
                                                      int* __restrict__ bincnt,
                                                      int* __restrict__ blockcnt) {
    __shared__ int cnt[NBINS];
    int t = threadIdx.x;
    for (int b = t; b < NBINS; b += 256) cnt[b] = 0;
    __syncthreads();
    int base = blockIdx.x * EPB_HIST;
    for (int i = 0; i < EPB_HIST / 256; ++i) {
        int e = base + i * 256 + t;
        if (e < N_EDGES) atomicAdd(&cnt[dst[e] >> 7], 1);
    }
    __syncthreads();
    for (int b = t; b < NBINS; b += 256) {
        int c = cnt[b];
        blockcnt[(size_t)blockIdx.x * NBINS + b] = c;
        if (c > 0) atomicAdd(&bincnt[b], c);
    }
}

__global__ __launch_bounds__(1024) void binscan_kernel(const int* __restrict__ bincnt,
                                                       int* __restrict__ binoff,
                                                       int* __restrict__ bincur) {
    __shared__ int s[1024];
    int t = threadIdx.x;
    int c = (t < NBINS) ? bincnt[t] : 0;
    s[t] = c;
    __syncthreads();
    for (int off = 1; off < 1024; off <<= 1) {
        int u = (t >= off) ? s[t - off] : 0;
        __syncthreads();
        s[t] += u;
        __syncthreads();
    }
    if (t < NBINS) { binoff[t] = s[t] - c; bincur[t] = s[t] - c; }
    if (t == 0) binoff[NBINS] = N_EDGES;
}

__global__ __launch_bounds__(256) void binscatter_kernel(const int* __restrict__ src,
                                                         const int* __restrict__ dst,
                                                         int* __restrict__ bincur,
                                                         unsigned* __restrict__ binbuf,
                                                         const int* __restrict__ blockcnt) {
    __shared__ int pos[NBINS];
    int t = threadIdx.x;
    for (int b = t; b < NBINS; b += 256) {
        int c = blockcnt[(size_t)blockIdx.x * NBINS + b];
        pos[b] = (c > 0) ? atomicAdd(&bincur[b], c) : 0;
    }
    __syncthreads();
    int base = blockIdx.x * EPB_HIST;
    for (int i = 0; i < EPB_HIST / 256; ++i) {
        int e = base + i * 256 + t;
        if (e < N_EDGES) {
            int d = dst[e];
            int bin = d >> 7;
            int p = atomicAdd(&pos[bin], 1);
            binbuf[p] = ((unsigned)(d & 127) << 17) | (unsigned)src[e];
        }
    }
}

// counting sort within bin -> exact per-node CSR, plain src in esrc
__global__ __launch_bounds__(256) void binsort_kernel(const unsigned* __restrict__ binbuf,
                                                      const int* __restrict__ binoff,
                                                      int* __restrict__ esrc,
                                                      int* __restrict__ nodeptr) {
    __shared__ int cnt[BIN_NODES];
    __shared__ int sc[BIN_NODES];
    int t = threadIdx.x;
    int bin = blockIdx.x;
    int beg = binoff[bin], end = binoff[bin + 1];
    if (t < BIN_NODES) cnt[t] = 0;
    __syncthreads();
    for (int e = beg + t; e < end; e += 256)
        atomicAdd(&cnt[binbuf[e] >> 17], 1);
    __syncthreads();
    int v = (t < BIN_NODES) ? cnt[t] : 0;
    if (t < BIN_NODES) sc[t] = v;
    __syncthreads();
    for (int off = 1; off < BIN_NODES; off <<= 1) {
        int u = (t < BIN_NODES && t >= off) ? sc[t - off] : 0;
        __syncthreads();
        if (t < BIN_NODES) sc[t] += u;
        __syncthreads();
    }
    if (t < BIN_NODES) {
        int excl = sc[t] - v;
        cnt[t] = excl;
        nodeptr[bin * BIN_NODES + t] = beg + excl;
    }
    __syncthreads();
    for (int e = beg + t; e < end; e += 256) {
        unsigned pe = binbuf[e];
        int dl = (int)(pe >> 17);
        int p = atomicAdd(&cnt[dl], 1);
        esrc[beg + p] = (int)(pe & 0x1FFFFu);
    }
}

// ===== fused GIN layer v3: MFMA-as-reducer. Wave owns a 16-node tile.
// D += A_i @ Wc over edge-ranks i (zero rows past degree); the matrix unit does the
// segment sum. No shuffle reduce, no unpack, no LDS atomics. Dual accumulator sets
// give 2 independent load->MFMA streams.
__global__ __launch_bounds__(256) void gin_fused_kernel(
        const unsigned short* __restrict__ xb,    // [N,32] bf16 layer input (padded)
        const int* __restrict__ esrc,             // node-grouped src ids
        const int* __restrict__ nodeptr,          // [>=N+1] monotone
        const unsigned short* __restrict__ Wcb, const float* __restrict__ shc,
        const unsigned short* __restrict__ Wlb, const float* __restrict__ shl,
        const int* __restrict__ batch, const float* __restrict__ lw_ptr,
        unsigned short* __restrict__ xnextb,      // bf16 out (may be null)
        float* __restrict__ xoutf,                // fp32 conv out (may be null)
        float* __restrict__ Z,                    // [N,32] +=
        unsigned* __restrict__ segmax)            // [G,32] encoded
{
    __shared__ __align__(16) unsigned short hl[4][16 * HLS];   // 5 KB
    __shared__ unsigned segloc[8 * DIM];                       // 1 KB
    int t = threadIdx.x;
    segloc[t] = 0;

    int wv = t >> 6, lane = t & 63;
    int m = lane & 15, kg = lane >> 4;

    // B fragments: B[k=kg*8+j][n=m]
    short8 bc0, bc1, bl0, bl1;
#pragma unroll
    for (int j = 0; j < 8; ++j) {
        int k = kg * 8 + j;
        bc0[j] = (short)Wcb[k * DIM + m];
        bc1[j] = (short)Wcb[k * DIM + 16 + m];
        bl0[j] = (short)Wlb[k * DIM + m];
        bl1[j] = (short)Wlb[k * DIM + 16 + m];
    }
    float shc0 = shc[m], shc1 = shc[m + 16];
    float shl0 = shl[m], shl1 = shl[m + 16];
    float lw = lw_ptr[0];
    int blk0 = blockIdx.x * 64;
    int gfirst = batch[blk0 < N_NODES ? blk0 : N_NODES - 1];
    int row0 = blk0 + wv * 16;
    __syncthreads();   // segloc init visible

    if (row0 < N_NODES) {                 // N%16==0: whole tile valid or wave idle
        int beg = nodeptr[row0 + m];
        int deg = nodeptr[row0 + m + 1] - beg;
        int md = deg;
#pragma unroll
        for (int off = 1; off < 16; off <<= 1)
            md = max(md, __shfl_xor(md, off, 64));   // max over the 16 rows

        // self row seeds stream A
        short8 aA = *(const short8*)(xb + (size_t)(row0 + m) * DIM + kg * 8);
        f32x4 d0a = {0.f, 0.f, 0.f, 0.f}, d1a = {0.f, 0.f, 0.f, 0.f};
        f32x4 d0b = {0.f, 0.f, 0.f, 0.f}, d1b = {0.f, 0.f, 0.f, 0.f};
        d0a = __builtin_amdgcn_mfma_f32_16x16x32_bf16(aA, bc0, d0a, 0, 0, 0);
        d1a = __builtin_amdgcn_mfma_f32_16x16x32_bf16(aA, bc1, d1a, 0, 0, 0);

        int i = 0;
        for (; i + 1 < md; i += 2) {      // two independent load->MFMA streams
            short8 a0 = {0, 0, 0, 0, 0, 0, 0, 0};
            short8 a1 = {0, 0, 0, 0, 0, 0, 0, 0};
            if (i < deg) {
                int s = esrc[beg + i];
                a0 = *(const short8*)(xb + (size_t)s * DIM + kg * 8);
            }
            if (i + 1 < deg) {
                int s = esrc[beg + i + 1];
                a1 = *(const short8*)(xb + (size_t)s * DIM + kg * 8);
            }
            d0a = __builtin_amdgcn_mfma_f32_16x16x32_bf16(a0, bc0, d0a, 0, 0, 0);
            d1a = __builtin_amdgcn_mfma_f32_16x16x32_bf16(a0, bc1, d1a, 0, 0, 0);
            d0b = __builtin_amdgcn_mfma_f32_16x16x32_bf16(a1, bc0, d0b, 0, 0, 0);
            d1b = __builtin_amdgcn_mfma_f32_16x16x32_bf16(a1, bc1, d1b, 0, 0, 0);
        }
        if (i < md) {
            short8 a0 = {0, 0, 0, 0, 0, 0, 0, 0};
            if (i < deg) {
                int s = esrc[beg + i];
                a0 = *(const short8*)(xb + (size_t)s * DIM + kg * 8);
            }
            d0a = __builtin_amdgcn_mfma_f32_16x16x32_bf16(a0, bc0, d0a, 0, 0, 0);
            d1a = __builtin_amdgcn_mfma_f32_16x16x32_bf16(a0, bc1, d1a, 0, 0, 0);
        }

        // conv epilogue: D-layout row = row0 + kg*4 + r, cols m / m+16
        float hp0[4], hp1[4];
#pragma unroll
        for (int r = 0; r < 4; ++r) {
            float a0 = d0a[r] + d0b[r] + shc0;
            float a1 = d1a[r] + d1b[r] + shc1;
            hp0[r] = a0 > 0.f ? a0 : expm1f(a0);
            hp1[r] = a1 > 0.f ? a1 : expm1f(a1);
        }
#pragma unroll
        for (int r = 0; r < 4; ++r) {     // D-layout -> row-major bf16 tile (same-wave LDS)
            hl[wv][(kg * 4 + r) * HLS + m] = f2bf(hp0[r]);
            hl[wv][(kg * 4 + r) * HLS + 16 + m] = f2bf(hp1[r]);
        }
        if (xoutf) {
#pragma unroll
            for (int r = 0; r < 4; ++r) {
                int row = row0 + kg * 4 + r;
                xoutf[(size_t)row * DIM + m] = hp0[r];
                xoutf[(size_t)row * DIM + 16 + m] = hp1[r];
            }
        }
        if (xnextb) {                     // coalesced bf16 out from LDS
            int ii = lane >> 2, q = lane & 3;
            uint4 pk = *(const uint4*)&hl[wv][ii * HLS + q * 8];
            *(uint4*)(xnextb + (size_t)(row0 + ii) * DIM + q * 8) = pk;
        }

        // lin MLP via MFMA
        short8 a2 = *(const short8*)&hl[wv][m * HLS + kg * 8];
        f32x4 e0 = {0.f, 0.f, 0.f, 0.f}, e1 = {0.f, 0.f, 0.f, 0.f};
        e0 = __builtin_amdgcn_mfma_f32_16x16x32_bf16(a2, bl0, e0, 0, 0, 0);
        e1 = __builtin_amdgcn_mfma_f32_16x16x32_bf16(a2, bl1, e1, 0, 0, 0);
#pragma unroll
        for (int r = 0; r < 4; ++r) {
            int row = row0 + kg * 4 + r;
            float a0 = e0[r] + shl0, a1 = e1[r] + shl1;
            float z0 = a0 > 0.f ? a0 : expm1f(a0);
            float z1 = a1 > 0.f ? a1 : expm1f(a1);
            float zw0 = lw * z0, zw1 = lw * z1;
            size_t zi = (size_t)row * DIM;
            Z[zi + m] += zw0;
            Z[zi + 16 + m] += zw1;
            int g = batch[row];
            int go = g - gfirst;
            if (go < 8) {
                atomicMax(&segloc[go * DIM + m], enc_f32(zw0));
                atomicMax(&segloc[go * DIM + 16 + m], enc_f32(zw1));
            } else {
                atomicMax(&segmax[g * DIM + m], enc_f32(zw0));
                atomicMax(&segmax[g * DIM + 16 + m], enc_f32(zw1));
            }
        }
    }
    __syncthreads();
    unsigned v = segloc[t];
    if (v) atomicMax(&segmax[(gfirst + (t >> 5)) * DIM + (t & 31)], v);
}

// ===== layer-0 lin MLP via MFMA; reads fp32 x0, emits bf16 mirror =====
__global__ __launch_bounds__(256) void linZ_first_kernel(
        const float* __restrict__ x0,
        unsigned short* __restrict__ x0b,
        const unsigned short* __restrict__ Wb,
        const float* __restrict__ shf,
        const int* __restrict__ batch,
        const float* __restrict__ lw_ptr,
        float* __restrict__ Z,
        unsigned* __restrict__ segmax)
{
    __shared__ unsigned segloc[8 * DIM];
    int t = threadIdx.x;
    segloc[t] = 0;

    int wv = t >> 6, lane = t & 63;
    int m = lane & 15, kg = lane >> 4;

    short8 b0, b1;
#pragma unroll
    for (int j = 0; j < 8; ++j) {
        int k = kg * 8 + j;
        b0[j] = (short)Wb[k * DIM + m];
        b1[j] = (short)Wb[k * DIM + 16 + m];
    }
    float sh0 = shf[m], sh1 = shf[m + 16];
    float lw = lw_ptr[0];
    int blk0 = blockIdx.x * 64;
    int gfirst = batch[blk0 < N_NODES ? blk0 : N_NODES - 1];
    int row0 = blk0 + wv * 16;
    __syncthreads();

    if (row0 < N_NODES) {
        const float* rp = x0 + (size_t)(row0 + m) * DIM + kg * 8;
        float4 v0 = *(const float4*)rp;
        float4 v1 = *(const float4*)(rp + 4);
        short8 a;
        a[0] = (short)f2bf(v0.x); a[1] = (short)f2bf(v0.y);
        a[2] = (short)f2bf(v0.z); a[3] = (short)f2bf(v0.w);
        a[4] = (short)f2bf(v1.x); a[5] = (short)f2bf(v1.y);
        a[6] = (short)f2bf(v1.z); a[7] = (short)f2bf(v1.w);
        *(short8*)(x0b + (size_t)(row0 + m) * DIM + kg * 8) = a;

        f32x4 d0 = {0.f, 0.f, 0.f, 0.f}, d1 = {0.f, 0.f, 0.f, 0.f};
        d0 = __builtin_amdgcn_mfma_f32_16x16x32_bf16(a, b0, d0, 0, 0, 0);
        d1 = __builtin_amdgcn_mfma_f32_16x16x32_bf16(a, b1, d1, 0, 0, 0);
#pragma unroll
        for (int r = 0; r < 4; ++r) {
            int row = row0 + kg * 4 + r;
            float a0 = d0[r] + sh0;
            float a1 = d1[r] + sh1;
            float z0 = a0 > 0.f ? a0 : expm1f(a0);
            float z1 = a1 > 0.f ? a1 : expm1f(a1);
            size_t zi = (size_t)row * DIM;
            Z[zi + m] = lw * z0;
            Z[zi + 16 + m] = lw * z1;
            int g = batch[row];
            int go = g - gfirst;
            if (go < 8) {
                atomicMax(&segloc[go * DIM + m], enc_f32(z0));
                atomicMax(&segloc[go * DIM + 16 + m], enc_f32(z1));
            } else {
                atomicMax(&segmax[g * DIM + m], enc_f32(z0));
                atomicMax(&segmax[g * DIM + 16 + m], enc_f32(z1));
            }
        }
    }
    __syncthreads();
    unsigned v = segloc[t];
    if (v) atomicMax(&segmax[(gfirst + (t >> 5)) * DIM + (t & 31)], v);
}

// out[g][j] += decode(segmax[g][j]); reset segmax for the next layer's atomics.
__global__ void add_out_kernel(unsigned* __restrict__ segmax, float* __restrict__ out) {
    int t = blockIdx.x * blockDim.x + threadIdx.x;  // 2048
    out[t] += dec_f32(segmax[t]);
    segmax[t] = 0;
}

extern "C" void kernel_launch(void* const* d_in, const int* in_sizes, int n_in,
                              void* d_out, int out_size, void* d_ws, size_t ws_size,
                              hipStream_t stream) {
    const float* x0        = (const float*)d_in[0];
    const int*   ei        = (const int*)d_in[1];     // (2,E): row0=src, row1=dst
    const int*   batch     = (const int*)d_in[2];
    const float* lw        = (const float*)d_in[3];
    const float* lin_W     = (const float*)d_in[4];
    const float* lin_b     = (const float*)d_in[5];
    const float* lin_gamma = (const float*)d_in[6];
    const float* lin_beta  = (const float*)d_in[7];
    const float* lin_mean  = (const float*)d_in[8];
    const float* lin_var   = (const float*)d_in[9];
    const float* conv_W    = (const float*)d_in[10];
    const float* conv_b    = (const float*)d_in[11];
    const float* conv_gamma= (const float*)d_in[12];
    const float* conv_beta = (const float*)d_in[13];
    const float* conv_mean = (const float*)d_in[14];
    const float* conv_var  = (const float*)d_in[15];

    float* out  = (float*)d_out;                 // [G*32]
    float* Z    = out + N_GROUPS * DIM;          // [N*32]
    float* xout = Z + (size_t)N_NODES * DIM;     // [N*32] final x (fp32 conv out, layer 2)

    char* p = (char*)d_ws;
    unsigned short* x0b     = (unsigned short*)p; p += ((size_t)N_NODES * DIM + 8192) * sizeof(unsigned short);
    unsigned short* xbufb   = (unsigned short*)p; p += ((size_t)N_NODES * DIM + 8192) * sizeof(unsigned short);
    unsigned*       binbuf  = (unsigned*)p;       p += (size_t)N_EDGES * sizeof(unsigned);
    int*            esrc    = (int*)p;            p += (size_t)N_EDGES * sizeof(int);
    int*            nodeptr = (int*)p;            p += (NBINS * BIN_NODES + 1) * sizeof(int);
    int*            blockcnt= (int*)p;            p += (size_t)HIST_BLOCKS * NBINS * sizeof(int);
    int*            bincnt  = (int*)p;            p += NBINS * sizeof(int);
    int*            binoff  = (int*)p;            p += (NBINS + 1) * sizeof(int);
    int*            bincur  = (int*)p;            p += NBINS * sizeof(int);
    unsigned*       segmx   = (unsigned*)p;       p += N_GROUPS * DIM * sizeof(unsigned);
    float*          Wf      = (float*)p;          p += 5 * DIM * DIM * sizeof(float);
    float*          shf     = (float*)p;          p += 5 * DIM * sizeof(float);
    unsigned short* Wfb     = (unsigned short*)p; p += 5 * DIM * DIM * sizeof(unsigned short);

    const int* src = ei;
    const int* dst = ei + N_EDGES;

    const int gf_blocks = (N_NODES + 63) / 64;   // 1563

    fold_kernel<<<6, 1024, 0, stream>>>(lin_W, lin_b, lin_gamma, lin_beta, lin_mean, lin_var,
                                        conv_W, conv_b, conv_gamma, conv_beta, conv_mean, conv_var,
                                        Wf, shf, Wfb, out, segmx, bincnt);

    // ---- CSR build ----
    binhist_kernel<<<HIST_BLOCKS, 256, 0, stream>>>(dst, bincnt, blockcnt);
    binscan_kernel<<<1, 1024, 0, stream>>>(bincnt, binoff, bincur);
    binscatter_kernel<<<HIST_BLOCKS, 256, 0, stream>>>(src, dst, bincur, binbuf, blockcnt);
    binsort_kernel<<<NBINS, 256, 0, stream>>>(binbuf, binoff, esrc, nodeptr);

    // ---- layer 0 (also emits x0b bf16 mirror) ----
    linZ_first_kernel<<<gf_blocks, 256, 0, stream>>>(x0, x0b, Wfb, shf, batch, lw, Z, segmx);
    add_out_kernel<<<8, 256, 0, stream>>>(segmx, out);

    // ---- layer 1 ----
    gin_fused_kernel<<<gf_blocks, 256, 0, stream>>>(x0b, esrc, nodeptr,
                                                    Wfb + 3 * DIM * DIM, shf + 3 * DIM,
                                                    Wfb + 1 * DIM * DIM, shf + 1 * DIM,
                                                    batch, lw + 1,
                                                    xbufb, (float*)nullptr, Z, segmx);
    add_out_kernel<<<8, 256, 0, stream>>>(segmx, out);

    // ---- layer 2 ----
    gin_fused_kernel<<<gf_blocks, 256, 0, stream>>>(xbufb, esrc, nodeptr,
                                                    Wfb + 4 * DIM * DIM, shf + 4 * DIM,
                                                    Wfb + 2 * DIM * DIM, shf + 2 * DIM,
                                                    batch, lw + 2,
                                                    (unsigned short*)nullptr, xout, Z, segmx);
    add_out_kernel<<<8, 256, 0, stream>>>(segmx, out);
}